// Round 1
// baseline (839.150 us; speedup 1.0000x reference)
//
#include <hip/hip_runtime.h>
#include <math.h>

// Problem constants (static graph dims from the reference)
#define BATCH   16384
#define IN_DIM  512
#define NH      128
#define NO      256
#define SRC_DIM 640                 // IN_DIM + NH
#define RPB     8                   // batch rows per block
#define SRC_STRIDE 648              // 640 + 8 pad (breaks power-of-2 bank aliasing)
#define OUT_STRIDE 264              // 256 + 8 pad
#define THREADS 256

__device__ __forceinline__ float fast_rcp(float x) {
    return __builtin_amdgcn_rcpf(x);
}

__device__ __forceinline__ float fast_exp2(float x) {
#if __has_builtin(__builtin_amdgcn_exp2f)
    return __builtin_amdgcn_exp2f(x);
#else
    return exp2f(x);
#endif
}

// act ids: 1=identity, 2=tanh, 3=relu, 4=sigmoid
// Branchless: one exp2 + one rcp covers both tanh and sigmoid.
//   tanh(z)    = 1 - 2/(exp2(2*L2E*z)+1)
//   sigmoid(z) = 1/(1+exp2(-L2E*z))

#define L2E 1.4426950408889634f

__global__ __launch_bounds__(THREADS)
void wann_kernel(const float* __restrict__ x,
                 const float* __restrict__ wh,
                 const float* __restrict__ wo,
                 const int* __restrict__ rows_h, const int* __restrict__ cols_h,
                 const int* __restrict__ acts_h,
                 const int* __restrict__ rows_o, const int* __restrict__ cols_o,
                 const int* __restrict__ acts_o,
                 float* __restrict__ out, int Eh, int Eo)
{
    __shared__ float src [RPB][SRC_STRIDE];   // cols 0..511 = x row, 512..639 = H accum
    __shared__ float outb[RPB][OUT_STRIDE];   // output accumulators

    const int tid = threadIdx.x;
    const int row_base = blockIdx.x * RPB;

    // ---- stage x rows into LDS (float4, fully coalesced) ----
    {
        const float4* xv = (const float4*)(x + (size_t)row_base * IN_DIM);
        // RPB*IN_DIM/4 = 1024 float4 over 256 threads -> 4 each
        #pragma unroll
        for (int k = 0; k < (RPB * IN_DIM / 4) / THREADS; ++k) {
            int v = tid + k * THREADS;
            int r = v >> 7;        // /128 float4 per row
            int i = v & 127;
            float4 val = xv[r * (IN_DIM / 4) + i];
            *(float4*)&src[r][i * 4] = val;
        }
    }
    // ---- zero H region (cols 512..647) and output accumulators ----
    for (int v = tid; v < RPB * (SRC_STRIDE - IN_DIM); v += THREADS) {
        int r = v / (SRC_STRIDE - IN_DIM);
        int c = v - r * (SRC_STRIDE - IN_DIM);
        src[r][IN_DIM + c] = 0.0f;
    }
    for (int v = tid; v < RPB * OUT_STRIDE; v += THREADS) {
        outb[v / OUT_STRIDE][v - (v / OUT_STRIDE) * OUT_STRIDE] = 0.0f;
    }
    __syncthreads();

    // ---- hidden edges: H[r][row] += act(x[r][col] * w) ----
    for (int e = tid; e < Eh; e += THREADS) {
        const int   col = cols_h[e];
        const int   row = rows_h[e];
        const int   a   = acts_h[e];
        const float w   = wh[e];
        const float k   = (a == 2) ? (2.0f * L2E) : ((a == 4) ? -L2E : 0.0f);
        #pragma unroll
        for (int r = 0; r < RPB; ++r) {
            float z  = src[r][col] * w;
            float ex = fast_exp2(k * z);
            float rc = fast_rcp(1.0f + ex);
            float res = (a == 2) ? (1.0f - 2.0f * rc)
                      : ((a == 4) ? rc
                      : ((a == 3) ? fmaxf(z, 0.0f) : z));
            atomicAdd(&src[r][IN_DIM + row], res);
        }
    }
    __syncthreads();

    // ---- output edges: out[r][row] += act(src[r][col] * w), col in [0,640) ----
    for (int e = tid; e < Eo; e += THREADS) {
        const int   col = cols_o[e];
        const int   row = rows_o[e];
        const int   a   = acts_o[e];
        const float w   = wo[e];
        const float k   = (a == 2) ? (2.0f * L2E) : ((a == 4) ? -L2E : 0.0f);
        #pragma unroll
        for (int r = 0; r < RPB; ++r) {
            float z  = src[r][col] * w;
            float ex = fast_exp2(k * z);
            float rc = fast_rcp(1.0f + ex);
            float res = (a == 2) ? (1.0f - 2.0f * rc)
                      : ((a == 4) ? rc
                      : ((a == 3) ? fmaxf(z, 0.0f) : z));
            atomicAdd(&outb[r][row], res);
        }
    }
    __syncthreads();

    // ---- epilogue: out = tanh(accum), coalesced store ----
    for (int v = tid; v < RPB * NO; v += THREADS) {
        int r = v >> 8;            // /256
        int c = v & 255;
        float s  = outb[r][c];
        float ex = fast_exp2(2.0f * L2E * s);
        float t  = 1.0f - 2.0f * fast_rcp(1.0f + ex);
        out[(size_t)(row_base + r) * NO + c] = t;
    }
}

extern "C" void kernel_launch(void* const* d_in, const int* in_sizes, int n_in,
                              void* d_out, int out_size, void* d_ws, size_t ws_size,
                              hipStream_t stream) {
    const float* x      = (const float*)d_in[0];
    const float* wh     = (const float*)d_in[1];
    const float* wo     = (const float*)d_in[2];
    const int*   rows_h = (const int*)d_in[3];
    const int*   cols_h = (const int*)d_in[4];
    const int*   acts_h = (const int*)d_in[5];
    const int*   rows_o = (const int*)d_in[6];
    const int*   cols_o = (const int*)d_in[7];
    const int*   acts_o = (const int*)d_in[8];
    float*       out    = (float*)d_out;

    const int Eh = in_sizes[1];   // wh has one weight per hidden edge
    const int Eo = in_sizes[2];   // wo has one weight per output edge

    dim3 grid(BATCH / RPB);       // 2048 blocks
    wann_kernel<<<grid, THREADS, 0, stream>>>(x, wh, wo,
                                              rows_h, cols_h, acts_h,
                                              rows_o, cols_o, acts_o,
                                              out, Eh, Eo);
}

// Round 2
// 231.789 us; speedup vs baseline: 3.6203x; 3.6203x over previous
//
#include <hip/hip_runtime.h>
#include <math.h>

// Problem constants (static graph dims from the reference)
#define BATCH   16384
#define IN_DIM  512
#define NH      128
#define NO      256
#define L2E     1.4426950408889634f

#define MAIN_THREADS 1024
#define NWAVE (MAIN_THREADS / 64)        // 16 waves
#define HROWS_PER_WAVE (NH / NWAVE)      // 8 hidden rows per wave
#define OROWS_PER_WAVE (NO / NWAVE)      // 16 output rows per wave
#define HSTRIDE 65                       // +1 pad: breaks stride-64 bank aliasing
#define OSTRIDE 65

__device__ __forceinline__ float fast_rcp(float x) { return __builtin_amdgcn_rcpf(x); }
__device__ __forceinline__ float fast_exp2(float x) {
#if __has_builtin(__builtin_amdgcn_exp2f)
    return __builtin_amdgcn_exp2f(x);
#else
    return exp2f(x);
#endif
}

// act ids: 1=identity, 2=tanh, 3=relu, 4=sigmoid. `a` is wave-uniform (SGPR)
// -> these are scalar branches, no divergence; only tanh/sigmoid edges pay exp2.
__device__ __forceinline__ float edge_act(float z, int a) {
    if (a == 2) { float ex = fast_exp2(2.f * L2E * z); return 1.f - 2.f * fast_rcp(1.f + ex); }
    if (a == 3) return fmaxf(z, 0.f);
    if (a == 4) { float ex = fast_exp2(-L2E * z); return fast_rcp(1.f + ex); }
    return z;
}
__device__ __forceinline__ float fast_tanh(float z) {
    float ex = fast_exp2(2.f * L2E * z);
    return 1.f - 2.f * fast_rcp(1.f + ex);
}

// ---------------- prep: CSR row offsets + packed edge records ----------------
__device__ __forceinline__ int lower_bound_dev(const int* arr, int n, int v) {
    int lo = 0, hi = n;
    while (lo < hi) { int m = (lo + hi) >> 1; if (arr[m] < v) lo = m + 1; else hi = m; }
    return lo;
}

__global__ void prep_kernel(const int* __restrict__ rows_h, const int* __restrict__ cols_h,
                            const int* __restrict__ acts_h, const float* __restrict__ wh,
                            const int* __restrict__ rows_o, const int* __restrict__ cols_o,
                            const int* __restrict__ acts_o, const float* __restrict__ wo,
                            int Eh, int Eo,
                            int* __restrict__ offs_h, int* __restrict__ offs_o,
                            int4* __restrict__ packed_h, int4* __restrict__ packed_o) {
    int t = blockIdx.x * blockDim.x + threadIdx.x;
    if (t <= NH) offs_h[t] = lower_bound_dev(rows_h, Eh, t);               // 129 entries
    else if (t <= NH + 1 + NO) {                                           // 257 entries
        int r = t - (NH + 1);
        offs_o[r] = lower_bound_dev(rows_o, Eo, r);
    }
    int u = t - (NH + 1 + NO + 1);
    if (u >= 0 && u < Eh)
        packed_h[u] = make_int4(cols_h[u], acts_h[u], __float_as_int(wh[u]), 0);
    u -= Eh;
    if (u >= 0 && u < Eo)
        packed_o[u] = make_int4(cols_o[u], acts_o[u], __float_as_int(wo[u]), 0);
}

// ---------------- transpose: x[B][IN] -> xt[IN][B] (64x64 LDS tiles) ----------------
__global__ __launch_bounds__(256)
void transpose_kernel(const float* __restrict__ x, float* __restrict__ xt) {
    __shared__ float tile[64 * 65];
    const int b0 = blockIdx.x * 64;
    const int c0 = blockIdx.y * 64;
    #pragma unroll
    for (int k = 0; k < 16; ++k) {
        int idx = threadIdx.x + k * 256;
        int r = idx >> 6, c = idx & 63;
        tile[r * 65 + c] = x[(size_t)(b0 + r) * IN_DIM + c0 + c];
    }
    __syncthreads();
    #pragma unroll
    for (int k = 0; k < 16; ++k) {
        int idx = threadIdx.x + k * 256;
        int c = idx >> 6, r = idx & 63;
        xt[(size_t)(c0 + c) * BATCH + b0 + r] = tile[r * 65 + c];
    }
}

// ---------------- main: lane = batch row, rows partitioned across waves ----------------
// No atomics: edges are row-sorted; each wave owns disjoint dest rows and
// accumulates each row's run in a register, one LDS write per row.
template <bool USE_XT>
__global__ __launch_bounds__(MAIN_THREADS)
void wann_main(const float* __restrict__ xsrc,    // xt[IN][B] if USE_XT else x[B][IN]
               const int* __restrict__ offs_h, const int* __restrict__ offs_o,
               const int4* __restrict__ packed_h, const int4* __restrict__ packed_o,
               float* __restrict__ out) {
    __shared__ float H[NH * HSTRIDE];     // 33.3 KB  H[row*65 + lane]
    __shared__ float OB[NO * OSTRIDE];    // 66.6 KB  OB[row*65 + lane]

    const int tid = threadIdx.x;
    const int lane = tid & 63;
    const int wv = tid >> 6;              // 0..15
    const int rb = blockIdx.x * 64;       // batch base for this block

    // phase 1: hidden rows [wv*8, wv*8+8)
    #pragma unroll 1
    for (int r = wv * HROWS_PER_WAVE; r < (wv + 1) * HROWS_PER_WAVE; ++r) {
        int e0 = __builtin_amdgcn_readfirstlane(offs_h[r]);
        int e1 = __builtin_amdgcn_readfirstlane(offs_h[r + 1]);
        float acc = 0.f;
        for (int e = e0; e < e1; ++e) {
            int4 p = packed_h[e];
            int col = __builtin_amdgcn_readfirstlane(p.x);
            int a   = __builtin_amdgcn_readfirstlane(p.y);
            float w = __int_as_float(__builtin_amdgcn_readfirstlane(p.z));
            float xv = USE_XT ? xsrc[(size_t)col * BATCH + rb + lane]
                              : xsrc[(size_t)(rb + lane) * IN_DIM + col];
            acc += edge_act(xv * w, a);
        }
        H[r * HSTRIDE + lane] = acc;      // rows with no edges get 0
    }
    __syncthreads();

    // phase 2: output rows [wv*16, wv*16+16); col<512 -> x, else -> H
    #pragma unroll 1
    for (int r = wv * OROWS_PER_WAVE; r < (wv + 1) * OROWS_PER_WAVE; ++r) {
        int e0 = __builtin_amdgcn_readfirstlane(offs_o[r]);
        int e1 = __builtin_amdgcn_readfirstlane(offs_o[r + 1]);
        float acc = 0.f;
        for (int e = e0; e < e1; ++e) {
            int4 p = packed_o[e];
            int col = __builtin_amdgcn_readfirstlane(p.x);
            int a   = __builtin_amdgcn_readfirstlane(p.y);
            float w = __int_as_float(__builtin_amdgcn_readfirstlane(p.z));
            float v;
            if (col < IN_DIM)
                v = USE_XT ? xsrc[(size_t)col * BATCH + rb + lane]
                           : xsrc[(size_t)(rb + lane) * IN_DIM + col];
            else
                v = H[(col - IN_DIM) * HSTRIDE + lane];
            acc += edge_act(v * w, a);
        }
        OB[r * OSTRIDE + lane] = acc;
    }
    __syncthreads();

    // epilogue: out[b][c] = tanh(OB[c][b-rb]); coalesced store, conflict-free LDS read
    #pragma unroll
    for (int it = 0; it < (64 * NO) / MAIN_THREADS; ++it) {
        int v = tid + it * MAIN_THREADS;
        int c = v & 255;                  // out column (consecutive across lanes)
        int r = v >> 8;                   // batch row within block
        out[(size_t)(rb + r) * NO + c] = fast_tanh(OB[c * OSTRIDE + r]);
    }
}

// ---------------- round-1 fallback (correct, slow) if ws too small ----------------
#define RPB     8
#define SRC_STRIDE 648
#define OUT_STRIDE_FB 264
__global__ __launch_bounds__(256)
void wann_fallback(const float* __restrict__ x, const float* __restrict__ wh,
                   const float* __restrict__ wo,
                   const int* __restrict__ rows_h, const int* __restrict__ cols_h,
                   const int* __restrict__ acts_h,
                   const int* __restrict__ rows_o, const int* __restrict__ cols_o,
                   const int* __restrict__ acts_o,
                   float* __restrict__ out, int Eh, int Eo) {
    __shared__ float src[RPB][SRC_STRIDE];
    __shared__ float outb[RPB][OUT_STRIDE_FB];
    const int tid = threadIdx.x;
    const int row_base = blockIdx.x * RPB;
    {
        const float4* xv = (const float4*)(x + (size_t)row_base * IN_DIM);
        #pragma unroll
        for (int k = 0; k < (RPB * IN_DIM / 4) / 256; ++k) {
            int v = tid + k * 256;
            int r = v >> 7, i = v & 127;
            *(float4*)&src[r][i * 4] = xv[r * (IN_DIM / 4) + i];
        }
    }
    for (int v = tid; v < RPB * (SRC_STRIDE - IN_DIM); v += 256) {
        int r = v / (SRC_STRIDE - IN_DIM);
        src[r][IN_DIM + (v - r * (SRC_STRIDE - IN_DIM))] = 0.0f;
    }
    for (int v = tid; v < RPB * OUT_STRIDE_FB; v += 256)
        outb[v / OUT_STRIDE_FB][v % OUT_STRIDE_FB] = 0.0f;
    __syncthreads();
    for (int e = tid; e < Eh; e += 256) {
        int col = cols_h[e], row = rows_h[e], a = acts_h[e];
        float w = wh[e];
        #pragma unroll
        for (int r = 0; r < RPB; ++r)
            atomicAdd(&src[r][IN_DIM + row], edge_act(src[r][col] * w, a));
    }
    __syncthreads();
    for (int e = tid; e < Eo; e += 256) {
        int col = cols_o[e], row = rows_o[e], a = acts_o[e];
        float w = wo[e];
        #pragma unroll
        for (int r = 0; r < RPB; ++r)
            atomicAdd(&outb[r][row], edge_act(src[r][col] * w, a));
    }
    __syncthreads();
    for (int v = tid; v < RPB * NO; v += 256) {
        int r = v >> 8, c = v & 255;
        out[(size_t)(row_base + r) * NO + c] = fast_tanh(outb[r][c]);
    }
}

extern "C" void kernel_launch(void* const* d_in, const int* in_sizes, int n_in,
                              void* d_out, int out_size, void* d_ws, size_t ws_size,
                              hipStream_t stream) {
    const float* x      = (const float*)d_in[0];
    const float* wh     = (const float*)d_in[1];
    const float* wo     = (const float*)d_in[2];
    const int*   rows_h = (const int*)d_in[3];
    const int*   cols_h = (const int*)d_in[4];
    const int*   acts_h = (const int*)d_in[5];
    const int*   rows_o = (const int*)d_in[6];
    const int*   cols_o = (const int*)d_in[7];
    const int*   acts_o = (const int*)d_in[8];
    float*       out    = (float*)d_out;

    const int Eh = in_sizes[1];
    const int Eo = in_sizes[2];

    // ws layout: [offs_h 129 ints @0][offs_o 257 ints @1024][packed_h @4096][packed_o][xt]
    char* ws = (char*)d_ws;
    int*  offs_h   = (int*)ws;
    int*  offs_o   = (int*)(ws + 1024);
    int4* packed_h = (int4*)(ws + 4096);
    int4* packed_o = packed_h + Eh;
    size_t tier2_need = 4096 + (size_t)(Eh + Eo) * 16;
    size_t xt_off     = (tier2_need + 255) & ~(size_t)255;
    float* xt         = (float*)(ws + xt_off);
    size_t full_need  = xt_off + (size_t)IN_DIM * BATCH * 4;

    if (ws_size >= tier2_need) {
        int ntasks = (NH + 1) + (NO + 1) + Eh + Eo;
        prep_kernel<<<(ntasks + 255) / 256, 256, 0, stream>>>(
            rows_h, cols_h, acts_h, wh, rows_o, cols_o, acts_o, wo,
            Eh, Eo, offs_h, offs_o, packed_h, packed_o);
        if (ws_size >= full_need) {
            transpose_kernel<<<dim3(BATCH / 64, IN_DIM / 64), 256, 0, stream>>>(x, xt);
            wann_main<true><<<BATCH / 64, MAIN_THREADS, 0, stream>>>(
                xt, offs_h, offs_o, packed_h, packed_o, out);
        } else {
            wann_main<false><<<BATCH / 64, MAIN_THREADS, 0, stream>>>(
                x, offs_h, offs_o, packed_h, packed_o, out);
        }
    } else {
        wann_fallback<<<BATCH / RPB, 256, 0, stream>>>(
            x, wh, wo, rows_h, cols_h, acts_h, rows_o, cols_o, acts_o, out, Eh, Eo);
    }
}